// Round 9
// baseline (528.614 us; speedup 1.0000x reference)
//
#include <hip/hip_runtime.h>
#include <hip/hip_bf16.h>

typedef __attribute__((ext_vector_type(8))) short short8;
typedef __attribute__((ext_vector_type(8))) unsigned short ushort8;
typedef __attribute__((ext_vector_type(4))) float f32x4;

static constexpr int NN = 50000;   // nodes
static constexpr int NE = 800000;  // edges
static constexpr int SCAN_B = 196; // ceil(NN/256)

#define MFMA16x16x32 __builtin_amdgcn_mfma_f32_16x16x32_bf16

__device__ __forceinline__ float b2f(unsigned short u){
  unsigned v = ((unsigned)u) << 16;
  return __builtin_bit_cast(float, v);
}
__device__ __forceinline__ unsigned short f2b(float f){
  unsigned x = __builtin_bit_cast(unsigned, f);
  unsigned r = (x + 0x7fffu + ((x >> 16) & 1u)) >> 16;  // RNE
  return (unsigned short)r;
}

// async 16B global->LDS copy (no VGPR round-trip; LDS dest = wave base + lane*16)
__device__ __forceinline__ void gld16(const void* g, void* l){
  __builtin_amdgcn_global_load_lds(
      (const __attribute__((address_space(1))) void*)g,
      (__attribute__((address_space(3))) void*)l, 16, 0, 0);
}

// ---------------- static device scratch
__device__ __align__(256) int   g_isf32;
__device__ __align__(256) unsigned short g_W1t  [112 * 512];
__device__ __align__(256) unsigned short g_W2t  [112 * 128];
__device__ __align__(256) unsigned short g_WselfT[112 * 128];
__device__ __align__(256) unsigned short g_WrelT [112 * 128];
__device__ __align__(256) unsigned short g_c1Wt [112 * 128];
__device__ __align__(256) unsigned short g_c2Wt [64 * 128];
__device__ __align__(256) unsigned short g_bufA[(size_t)NN * 128];
__device__ __align__(256) unsigned short g_bufB[(size_t)NN * 128];
__device__ __align__(256) unsigned short g_bufC[(size_t)NN * 128];
__device__ __align__(256) int   g_deg[NN];
__device__ __align__(256) int   g_rowptr[NN + 1];
__device__ __align__(256) int   g_cursor[NN];
__device__ __align__(256) int   g_colidx[NE];
__device__ __align__(256) float g_dinv[NN];
__device__ __align__(256) int   g_partial[256];

__device__ __forceinline__ float ld_in(const void* p, int idx, int isf32){
  if (isf32) return ((const float*)p)[idx];
  return b2f(((const unsigned short*)p)[idx]);
}

// ---------------- dtype sniffer
__global__ void k_detect(const unsigned short* __restrict__ x){
  __shared__ int sh[256];
  int tid = threadIdx.x;
  int cnt = 0;
  for (int j = 0; j < 16; j++){
    unsigned short h = x[(size_t)(tid * 16 + j) * 2];
    int e = (h >> 7) & 0xFF;
    if (e >= 90 && e <= 160) cnt++;
  }
  sh[tid] = cnt;
  __syncthreads();
  for (int off = 128; off > 0; off >>= 1){
    if (tid < off) sh[tid] += sh[tid + off];
    __syncthreads();
  }
  if (tid == 0) g_isf32 = (sh[0] < 2458) ? 1 : 0;
}

// ---------------- zero deg/cursor
__global__ void k_zero(){
  int i = blockIdx.x * 256 + threadIdx.x;
  if (i < NN){ g_deg[i] = 0; g_cursor[i] = 0; }
}

// ---------------- all 6 weight transposes in ONE launch
__device__ __forceinline__ void xp_one(const void* W, unsigned short* Wt, int idx,
                                       int K, int Nc, int Kpad, int isf32){
  int n = idx / Kpad;
  int k = idx - n * Kpad;
  float v = 0.f;
  if (n < Nc && k < K) v = ld_in(W, k * Nc + n, isf32);
  Wt[idx] = f2b(v);
}
__global__ void k_transpose_all(const void* W1, const void* W2, const void* Wself,
                                const void* Wrel, const void* c1W, const void* c2W){
  int idx = blockIdx.x * 256 + threadIdx.x;
  const int isf32 = g_isf32;
  if (idx < 57344){ xp_one(W1, g_W1t, idx, 500, 100, 512, isf32); return; }
  idx -= 57344;
  if (idx < 14336){ xp_one(W2,    g_W2t,    idx, 100, 100, 128, isf32); return; }
  idx -= 14336;
  if (idx < 14336){ xp_one(Wself, g_WselfT, idx, 100, 100, 128, isf32); return; }
  idx -= 14336;
  if (idx < 14336){ xp_one(Wrel,  g_WrelT,  idx, 100, 100, 128, isf32); return; }
  idx -= 14336;
  if (idx < 14336){ xp_one(c1W,   g_c1Wt,   idx, 100, 100, 128, isf32); return; }
  idx -= 14336;
  if (idx < 8192){  xp_one(c2W,   g_c2Wt,   idx, 100, 64,  128, isf32); }
}

// ---------------- degree histogram
__global__ void k_deg(const int* __restrict__ tgt){
  int e = blockIdx.x * 256 + threadIdx.x;
  if (e < NE) atomicAdd(&g_deg[tgt[e]], 1);
}

// ---------------- two-level scan (scan1 fuses dinv)
__global__ __launch_bounds__(256) void k_scan1(){
  __shared__ int sh[256];
  int t = threadIdx.x;
  int i = blockIdx.x * 256 + t;
  int val = (i < NN) ? g_deg[i] : 0;
  sh[t] = val;
  __syncthreads();
#pragma unroll
  for (int off = 1; off < 256; off <<= 1){
    int v = (t >= off) ? sh[t - off] : 0;
    __syncthreads();
    sh[t] += v;
    __syncthreads();
  }
  if (i < NN){
    g_rowptr[i] = sh[t] - val;
    g_dinv[i] = rsqrtf((float)(val + 1));
  }
  if (t == 255) g_partial[blockIdx.x] = sh[255];
}
__global__ __launch_bounds__(256) void k_scan2(){
  __shared__ int sh[256];
  int t = threadIdx.x;
  int val = (t < SCAN_B) ? g_partial[t] : 0;
  sh[t] = val;
  __syncthreads();
#pragma unroll
  for (int off = 1; off < 256; off <<= 1){
    int v = (t >= off) ? sh[t - off] : 0;
    __syncthreads();
    sh[t] += v;
    __syncthreads();
  }
  if (t < SCAN_B) g_partial[t] = sh[t] - val;
  if (t == 255) g_rowptr[NN] = sh[255];
}
__global__ __launch_bounds__(256) void k_scan3(){
  int i = blockIdx.x * 256 + threadIdx.x;
  if (i < NN) g_rowptr[i] += g_partial[blockIdx.x];
}

// ---------------- CSR fill
__global__ void k_fill(const int* __restrict__ src, const int* __restrict__ tgt){
  int e = blockIdx.x * 256 + threadIdx.x;
  if (e >= NE) return;
  int t = tgt[e];
  int pos = g_rowptr[t] + atomicAdd(&g_cursor[t], 1);
  g_colidx[pos] = src[e];
}

// ---------------- gather-aggregate, high-MLP (16 lanes/node, x4 unroll)
template<int MODE>
__global__ __launch_bounds__(256) void k_agg(){
  const unsigned short* x = (MODE == 1) ? g_bufC : g_bufB;
  int node = blockIdx.x * 16 + (threadIdx.x >> 4);
  if (node >= NN) return;
  const int c8 = (threadIdx.x & 15) * 8;

  float wt = (MODE != 0) ? g_dinv[node] : 1.f;
  float a[4][8];
#pragma unroll
  for (int j = 0; j < 4; j++)
#pragma unroll
    for (int k = 0; k < 8; k++) a[j][k] = 0.f;

  int p0 = g_rowptr[node], p1 = g_rowptr[node + 1];
  for (int p = p0; p < p1; p += 4){
    int   sj[4]; float wj[4];
#pragma unroll
    for (int j = 0; j < 4; j++){
      bool ok = (p + j) < p1;
      sj[j] = ok ? g_colidx[p + j] : node;
      wj[j] = ok ? ((MODE != 0) ? g_dinv[sj[j]] * wt : 1.f) : 0.f;
    }
    ushort8 r[4];
#pragma unroll
    for (int j = 0; j < 4; j++)
      r[j] = *reinterpret_cast<const ushort8*>(&x[(size_t)sj[j] * 128 + c8]);
#pragma unroll
    for (int j = 0; j < 4; j++)
#pragma unroll
      for (int k = 0; k < 8; k++) a[j][k] += wj[j] * b2f((unsigned short)r[j][k]);
  }
  if (MODE != 0){
    float ws = wt * wt;
    ushort8 sv = *reinterpret_cast<const ushort8*>(&x[(size_t)node * 128 + c8]);
#pragma unroll
    for (int k = 0; k < 8; k++) a[0][k] += ws * b2f((unsigned short)sv[k]);
  }
  ushort8 o;
#pragma unroll
  for (int k = 0; k < 8; k++)
    o[k] = f2b(a[0][k] + a[1][k] + a[2][k] + a[3][k]);
  *reinterpret_cast<ushort8*>(&g_bufA[(size_t)node * 128 + c8]) = o;
}

// ---------------- GEMM1 (data_x [N,500] f32 -> bufA): wave-private async-LDS
// pipeline. 3125 blocks x 1 wave, 16 rows/wave (exact). Per K-chunk (128 f32):
// 8x global_load_lds (1KB each, no VGPR round-trip) into a private LDS
// double-buffer; ordering by s_waitcnt vmcnt(8) only -- NO barriers, so next
// chunk's copies stay in flight across compute (AITER-style fine vmcnt).
// LDS layout per chunk: inst j holds rows 2j,2j+1 (512B each):
//   f32 index of (row r, col c) = (r>>1)*256 + (r&1)*128 + c.
// K-tail: per-lane col clamped to 496 (finite dup values hit W1t zero-pad).
__global__ __launch_bounds__(64, 1) void k_gemm1_ln(const void* __restrict__ Aext,
    const void* __restrict__ bias, const void* __restrict__ gamma,
    const void* __restrict__ beta){
  __shared__ float sA[2][2048];   // 2 x 8KB
  const int lane = threadIdx.x;
  const int m = lane & 15, q = lane >> 4;
  const int row0 = blockIdx.x * 16;
  const int isf32 = g_isf32;
  f32x4 acc[7] = {};

  if (isf32){
    const float* X = (const float*)Aext;
    const int jr = lane >> 5;          // sub-row within inst (0/1)
    const int cg = (lane & 31) * 4;    // f32 col granule base
    // issue chunk 0
#pragma unroll
    for (int j = 0; j < 8; j++)
      gld16(X + (size_t)(row0 + 2 * j + jr) * 500 + min(cg, 496), &sA[0][j * 256]);
#pragma unroll
    for (int kc = 0; kc < 4; kc++){
      if (kc < 3){
        const int gc = (kc + 1) * 128 + cg;
#pragma unroll
        for (int j = 0; j < 8; j++)
          gld16(X + (size_t)(row0 + 2 * j + jr) * 500 + min(gc, 496),
                &sA[(kc + 1) & 1][j * 256]);
        __builtin_amdgcn_s_waitcnt(0x0F78);  // vmcnt<=8: chunk kc done, kc+1 in flight
      } else {
        __builtin_amdgcn_s_waitcnt(0x0F70);  // vmcnt(0): last chunk done
      }
      const float* sb = sA[kc & 1];
      const int ridx = (m >> 1) * 256 + (m & 1) * 128;
#pragma unroll
      for (int c = 0; c < 4; c++){
        const int kq = c * 32 + q * 8;
        f32x4 lo = *reinterpret_cast<const f32x4*>(sb + ridx + kq);
        f32x4 hi = *reinterpret_cast<const f32x4*>(sb + ridx + kq + 4);
        short8 a = {(short)f2b(lo[0]), (short)f2b(lo[1]), (short)f2b(lo[2]), (short)f2b(lo[3]),
                    (short)f2b(hi[0]), (short)f2b(hi[1]), (short)f2b(hi[2]), (short)f2b(hi[3])};
        const int k0 = kc * 128 + kq;
#pragma unroll
        for (int t = 0; t < 7; t++){
          short8 b = *reinterpret_cast<const short8*>(g_W1t + (size_t)(t * 16 + m) * 512 + k0);
          acc[t] = MFMA16x16x32(a, b, acc[t], 0, 0, 0);
        }
      }
    }
  } else {
    // bf16-input fallback (register path; unused when inputs are f32)
    const unsigned short* arow = (const unsigned short*)Aext + (size_t)(row0 + m) * 500;
    const int kq = q * 8;
#pragma unroll
    for (int c = 0; c < 16; c++){
      int kb = c * 32 + kq;
      ushort4 lo = *reinterpret_cast<const ushort4*>(arow + min(kb, 496));
      ushort4 hi = *reinterpret_cast<const ushort4*>(arow + min(kb + 4, 496));
      short8 a = {(short)lo.x, (short)lo.y, (short)lo.z, (short)lo.w,
                  (short)hi.x, (short)hi.y, (short)hi.z, (short)hi.w};
#pragma unroll
      for (int t = 0; t < 7; t++){
        short8 b = *reinterpret_cast<const short8*>(g_W1t + (size_t)(t * 16 + m) * 512 + kb);
        acc[t] = MFMA16x16x32(a, b, acc[t], 0, 0, 0);
      }
    }
  }

  // epilogue: +bias, LN over 100 cols, ReLU -> g_bufA [N,128]
  float bf_[7], gf_[7], ef_[7];
#pragma unroll
  for (int t = 0; t < 7; t++){
    int col = t * 16 + m;
    bool ok = col < 100;
    bf_[t] = ok ? ld_in(bias, col, isf32)  : 0.f;
    gf_[t] = ok ? ld_in(gamma, col, isf32) : 0.f;
    ef_[t] = ok ? ld_in(beta, col, isf32)  : 0.f;
  }
#pragma unroll
  for (int r = 0; r < 4; r++){
    float vals[7], s1 = 0.f, s2 = 0.f;
#pragma unroll
    for (int t = 0; t < 7; t++){
      int col = t * 16 + m;
      float v = (col < 100) ? (acc[t][r] + bf_[t]) : 0.f;
      vals[t] = v; s1 += v; s2 += v * v;
    }
#pragma unroll
    for (int msk = 1; msk < 16; msk <<= 1){
      s1 += __shfl_xor(s1, msk, 64);
      s2 += __shfl_xor(s2, msk, 64);
    }
    float mu = s1 * 0.01f;
    float var = fmaxf(s2 * 0.01f - mu * mu, 0.f);
    float rstd = rsqrtf(var + 1e-5f);
    unsigned short* orow = g_bufA + (size_t)(row0 + q * 4 + r) * 128;
#pragma unroll
    for (int t = 0; t < 7; t++){
      int col = t * 16 + m;
      float y = fmaxf((vals[t] - mu) * rstd * gf_[t] + ef_[t], 0.f);
      orow[col] = f2b((col < 100) ? y : 0.f);
    }
    orow[112 + m] = 0;
  }
}

// ---------------- GEMM2 + LN + ReLU (bufA [N,128] @ W2t -> bufB)
__global__ __launch_bounds__(256) void k_gemm2_ln(const void* __restrict__ bias,
    const void* __restrict__ gamma, const void* __restrict__ beta){
  const int isf32 = g_isf32;
  const int wave = threadIdx.x >> 6, lane = threadIdx.x & 63;
  const int m = lane & 15, q = lane >> 4;
  const int row0 = (blockIdx.x * 4 + wave) * 16;
  if (row0 >= NN) return;
  f32x4 acc[7] = {};
  const unsigned short* arow = g_bufA + (size_t)(row0 + m) * 128;
#pragma unroll
  for (int c = 0; c < 4; c++){
    const int k0 = c * 32 + q * 8;
    short8 a = *reinterpret_cast<const short8*>(arow + k0);
#pragma unroll
    for (int t = 0; t < 7; t++){
      short8 b = *reinterpret_cast<const short8*>(g_W2t + (size_t)(t * 16 + m) * 128 + k0);
      acc[t] = MFMA16x16x32(a, b, acc[t], 0, 0, 0);
    }
  }
  float bf_[7], gf_[7], ef_[7];
#pragma unroll
  for (int t = 0; t < 7; t++){
    int col = t * 16 + m;
    bool ok = col < 100;
    bf_[t] = ok ? ld_in(bias, col, isf32)  : 0.f;
    gf_[t] = ok ? ld_in(gamma, col, isf32) : 0.f;
    ef_[t] = ok ? ld_in(beta, col, isf32)  : 0.f;
  }
#pragma unroll
  for (int r = 0; r < 4; r++){
    float vals[7], s1 = 0.f, s2 = 0.f;
#pragma unroll
    for (int t = 0; t < 7; t++){
      int col = t * 16 + m;
      float v = (col < 100) ? (acc[t][r] + bf_[t]) : 0.f;
      vals[t] = v; s1 += v; s2 += v * v;
    }
#pragma unroll
    for (int msk = 1; msk < 16; msk <<= 1){
      s1 += __shfl_xor(s1, msk, 64);
      s2 += __shfl_xor(s2, msk, 64);
    }
    float mu = s1 * 0.01f;
    float var = fmaxf(s2 * 0.01f - mu * mu, 0.f);
    float rstd = rsqrtf(var + 1e-5f);
    unsigned short* orow = g_bufB + (size_t)(row0 + q * 4 + r) * 128;
#pragma unroll
    for (int t = 0; t < 7; t++){
      int col = t * 16 + m;
      float y = fmaxf((vals[t] - mu) * rstd * gf_[t] + ef_[t], 0.f);
      orow[col] = f2b((col < 100) ? y : 0.f);
    }
    orow[112 + m] = 0;
  }
}

// ---------------- (A1@B1t [+ A2@B2t]) + bias, ReLU. K=128.
template<int SEL>
__global__ __launch_bounds__(256) void k_gemm_bias_relu(const void* __restrict__ bias){
  const unsigned short* A1  = (SEL == 0) ? g_bufB : g_bufA;
  const unsigned short* B1t = (SEL == 0) ? g_WselfT : g_c1Wt;
  unsigned short* out       = (SEL == 0) ? g_bufC : g_bufB;
  const int isf32 = g_isf32;

  const int wave = threadIdx.x >> 6, lane = threadIdx.x & 63;
  const int m = lane & 15, q = lane >> 4;
  const int row0 = (blockIdx.x * 4 + wave) * 16;
  if (row0 >= NN) return;
  f32x4 acc[7] = {};
  const unsigned short* a1row = A1 + (size_t)(row0 + m) * 128;
#pragma unroll
  for (int c = 0; c < 4; c++){
    const int k0 = c * 32 + q * 8;
    short8 a = *reinterpret_cast<const short8*>(a1row + k0);
#pragma unroll
    for (int t = 0; t < 7; t++){
      short8 b = *reinterpret_cast<const short8*>(B1t + (size_t)(t * 16 + m) * 128 + k0);
      acc[t] = MFMA16x16x32(a, b, acc[t], 0, 0, 0);
    }
  }
  if (SEL == 0){
    const unsigned short* a2row = g_bufA + (size_t)(row0 + m) * 128;
#pragma unroll
    for (int c = 0; c < 4; c++){
      const int k0 = c * 32 + q * 8;
      short8 a = *reinterpret_cast<const short8*>(a2row + k0);
#pragma unroll
      for (int t = 0; t < 7; t++){
        short8 b = *reinterpret_cast<const short8*>(g_WrelT + (size_t)(t * 16 + m) * 128 + k0);
        acc[t] = MFMA16x16x32(a, b, acc[t], 0, 0, 0);
      }
    }
  }
  float bf_[7];
#pragma unroll
  for (int t = 0; t < 7; t++){
    int col = t * 16 + m;
    bf_[t] = (col < 100) ? ld_in(bias, col, isf32) : 0.f;
  }
#pragma unroll
  for (int r = 0; r < 4; r++){
    unsigned short* orow = out + (size_t)(row0 + q * 4 + r) * 128;
#pragma unroll
    for (int t = 0; t < 7; t++){
      int col = t * 16 + m;
      float y = fmaxf(acc[t][r] + bf_[t], 0.f);
      orow[col] = f2b((col < 100) ? y : 0.f);
    }
    orow[112 + m] = 0;
  }
}

// ---------------- bufA@c2Wt + bias -> log_softmax -> d_out [N,64]
__global__ __launch_bounds__(256) void k_gemm_lsm(const void* __restrict__ bias,
                                                  void* __restrict__ outv){
  const int isf32 = g_isf32;
  const int wave = threadIdx.x >> 6, lane = threadIdx.x & 63;
  const int m = lane & 15, q = lane >> 4;
  const int row0 = (blockIdx.x * 4 + wave) * 16;
  if (row0 >= NN) return;
  f32x4 acc[4] = {};
  const unsigned short* arow = g_bufA + (size_t)(row0 + m) * 128;
#pragma unroll
  for (int c = 0; c < 4; c++){
    const int k0 = c * 32 + q * 8;
    short8 a = *reinterpret_cast<const short8*>(arow + k0);
#pragma unroll
    for (int t = 0; t < 4; t++){
      short8 b = *reinterpret_cast<const short8*>(g_c2Wt + (size_t)(t * 16 + m) * 128 + k0);
      acc[t] = MFMA16x16x32(a, b, acc[t], 0, 0, 0);
    }
  }
  float bf_[4];
#pragma unroll
  for (int t = 0; t < 4; t++) bf_[t] = ld_in(bias, t * 16 + m, isf32);
#pragma unroll
  for (int r = 0; r < 4; r++){
    float vals[4], mx = -1e30f;
#pragma unroll
    for (int t = 0; t < 4; t++){
      float v = acc[t][r] + bf_[t];
      vals[t] = v; mx = fmaxf(mx, v);
    }
#pragma unroll
    for (int msk = 1; msk < 16; msk <<= 1) mx = fmaxf(mx, __shfl_xor(mx, msk, 64));
    float se = 0.f;
#pragma unroll
    for (int t = 0; t < 4; t++) se += expf(vals[t] - mx);
#pragma unroll
    for (int msk = 1; msk < 16; msk <<= 1) se += __shfl_xor(se, msk, 64);
    float lse = logf(se);
    size_t ro = (size_t)(row0 + q * 4 + r) * 64;
    if (isf32){
      float* orow = (float*)outv + ro;
#pragma unroll
      for (int t = 0; t < 4; t++) orow[t * 16 + m] = vals[t] - mx - lse;
    } else {
      unsigned short* orow = (unsigned short*)outv + ro;
#pragma unroll
      for (int t = 0; t < 4; t++) orow[t * 16 + m] = f2b(vals[t] - mx - lse);
    }
  }
}

extern "C" void kernel_launch(void* const* d_in, const int* in_sizes, int n_in,
                              void* d_out, int out_size, void* d_ws, size_t ws_size,
                              hipStream_t stream){
  (void)in_sizes; (void)n_in; (void)out_size; (void)d_ws; (void)ws_size;
  const void* data_x = d_in[0];
  const int* ei = (const int*)d_in[1];
  const int* src = ei;
  const int* tgt = ei + NE;
  const void *W1 = d_in[3], *b1 = d_in[4], *gm1 = d_in[5], *be1 = d_in[6];
  const void *W2 = d_in[7], *b2 = d_in[8], *gm2 = d_in[9], *be2 = d_in[10];
  const void *Wrel = d_in[11], *Wself = d_in[12], *rb = d_in[13];
  const void *c1W = d_in[14], *c1b = d_in[15];
  const void *c2W = d_in[16], *c2b = d_in[17];

  k_detect<<<1, 256, 0, stream>>>((const unsigned short*)data_x);
  k_zero<<<(NN + 255) / 256, 256, 0, stream>>>();
  k_transpose_all<<<(122880 + 255) / 256, 256, 0, stream>>>(W1, W2, Wself, Wrel, c1W, c2W);

  k_deg<<<(NE + 255) / 256, 256, 0, stream>>>(tgt);
  k_scan1<<<SCAN_B, 256, 0, stream>>>();
  k_scan2<<<1, 256, 0, stream>>>();
  k_scan3<<<SCAN_B, 256, 0, stream>>>();
  k_fill<<<(NE + 255) / 256, 256, 0, stream>>>(src, tgt);

  const int G64 = (NN + 63) / 64;     // 782 blocks, 4 waves x 16 rows
  const int GA  = (NN + 15) / 16;     // 3125 blocks, 16 nodes/block
  k_gemm1_ln<<<3125, 64, 0, stream>>>(data_x, b1, gm1, be1);   // data_x -> bufA
  k_gemm2_ln<<<G64, 256, 0, stream>>>(b2, gm2, be2);           // bufA -> bufB
  k_agg<0><<<GA, 256, 0, stream>>>();                          // bufB -> bufA (RGCN sum)
  k_gemm_bias_relu<0><<<G64, 256, 0, stream>>>(rb);            // bufB@Wself + bufA@Wrel -> bufC
  k_agg<1><<<GA, 256, 0, stream>>>();                          // bufC -> bufA (GCN norm)
  k_gemm_bias_relu<1><<<G64, 256, 0, stream>>>(c1b);           // bufA@c1W -> bufB
  k_agg<2><<<GA, 256, 0, stream>>>();                          // bufB -> bufA (GCN norm)
  k_gemm_lsm<<<G64, 256, 0, stream>>>(c2b, d_out);
}

// Round 10
// 507.074 us; speedup vs baseline: 1.0425x; 1.0425x over previous
//
#include <hip/hip_runtime.h>
#include <hip/hip_bf16.h>

typedef __attribute__((ext_vector_type(8))) short short8;
typedef __attribute__((ext_vector_type(8))) unsigned short ushort8;
typedef __attribute__((ext_vector_type(4))) float f32x4;

static constexpr int NN = 50000;   // nodes
static constexpr int NE = 800000;  // edges
static constexpr int SCAN_B = 196; // ceil(NN/256)

#define MFMA16x16x32 __builtin_amdgcn_mfma_f32_16x16x32_bf16

__device__ __forceinline__ float b2f(unsigned short u){
  unsigned v = ((unsigned)u) << 16;
  return __builtin_bit_cast(float, v);
}
__device__ __forceinline__ unsigned short f2b(float f){
  unsigned x = __builtin_bit_cast(unsigned, f);
  unsigned r = (x + 0x7fffu + ((x >> 16) & 1u)) >> 16;  // RNE
  return (unsigned short)r;
}

// ---------------- static device scratch
__device__ __align__(256) int   g_isf32;
__device__ __align__(256) unsigned short g_W1t  [112 * 512];
__device__ __align__(256) unsigned short g_W2t  [112 * 128];
__device__ __align__(256) unsigned short g_WselfT[112 * 128];
__device__ __align__(256) unsigned short g_WrelT [112 * 128];
__device__ __align__(256) unsigned short g_c1Wt [112 * 128];
__device__ __align__(256) unsigned short g_c2Wt [64 * 128];
__device__ __align__(256) unsigned short g_bufA[(size_t)NN * 128];
__device__ __align__(256) unsigned short g_bufB[(size_t)NN * 128];
__device__ __align__(256) unsigned short g_bufC[(size_t)NN * 128];
__device__ __align__(256) int   g_deg[NN];
__device__ __align__(256) int   g_rowptr[NN + 1];
__device__ __align__(256) int   g_cursor[NN];
__device__ __align__(256) int   g_colidx[NE];
__device__ __align__(256) float g_dinv[NN];
__device__ __align__(256) int   g_partial[256];

__device__ __forceinline__ float ld_in(const void* p, int idx, int isf32){
  if (isf32) return ((const float*)p)[idx];
  return b2f(((const unsigned short*)p)[idx]);
}

// ---------------- dtype sniffer
__global__ void k_detect(const unsigned short* __restrict__ x){
  __shared__ int sh[256];
  int tid = threadIdx.x;
  int cnt = 0;
  for (int j = 0; j < 16; j++){
    unsigned short h = x[(size_t)(tid * 16 + j) * 2];
    int e = (h >> 7) & 0xFF;
    if (e >= 90 && e <= 160) cnt++;
  }
  sh[tid] = cnt;
  __syncthreads();
  for (int off = 128; off > 0; off >>= 1){
    if (tid < off) sh[tid] += sh[tid + off];
    __syncthreads();
  }
  if (tid == 0) g_isf32 = (sh[0] < 2458) ? 1 : 0;
}

// ---------------- zero deg/cursor
__global__ void k_zero(){
  int i = blockIdx.x * 256 + threadIdx.x;
  if (i < NN){ g_deg[i] = 0; g_cursor[i] = 0; }
}

// ---------------- all 6 weight transposes in ONE launch
__device__ __forceinline__ void xp_one(const void* W, unsigned short* Wt, int idx,
                                       int K, int Nc, int Kpad, int isf32){
  int n = idx / Kpad;
  int k = idx - n * Kpad;
  float v = 0.f;
  if (n < Nc && k < K) v = ld_in(W, k * Nc + n, isf32);
  Wt[idx] = f2b(v);
}
__global__ void k_transpose_all(const void* W1, const void* W2, const void* Wself,
                                const void* Wrel, const void* c1W, const void* c2W){
  int idx = blockIdx.x * 256 + threadIdx.x;
  const int isf32 = g_isf32;
  if (idx < 57344){ xp_one(W1, g_W1t, idx, 500, 100, 512, isf32); return; }
  idx -= 57344;
  if (idx < 14336){ xp_one(W2,    g_W2t,    idx, 100, 100, 128, isf32); return; }
  idx -= 14336;
  if (idx < 14336){ xp_one(Wself, g_WselfT, idx, 100, 100, 128, isf32); return; }
  idx -= 14336;
  if (idx < 14336){ xp_one(Wrel,  g_WrelT,  idx, 100, 100, 128, isf32); return; }
  idx -= 14336;
  if (idx < 14336){ xp_one(c1W,   g_c1Wt,   idx, 100, 100, 128, isf32); return; }
  idx -= 14336;
  if (idx < 8192){  xp_one(c2W,   g_c2Wt,   idx, 100, 64,  128, isf32); }
}

// ---------------- degree histogram
__global__ void k_deg(const int* __restrict__ tgt){
  int e = blockIdx.x * 256 + threadIdx.x;
  if (e < NE) atomicAdd(&g_deg[tgt[e]], 1);
}

// ---------------- two-level scan (scan1 fuses dinv)
__global__ __launch_bounds__(256) void k_scan1(){
  __shared__ int sh[256];
  int t = threadIdx.x;
  int i = blockIdx.x * 256 + t;
  int val = (i < NN) ? g_deg[i] : 0;
  sh[t] = val;
  __syncthreads();
#pragma unroll
  for (int off = 1; off < 256; off <<= 1){
    int v = (t >= off) ? sh[t - off] : 0;
    __syncthreads();
    sh[t] += v;
    __syncthreads();
  }
  if (i < NN){
    g_rowptr[i] = sh[t] - val;
    g_dinv[i] = rsqrtf((float)(val + 1));
  }
  if (t == 255) g_partial[blockIdx.x] = sh[255];
}
__global__ __launch_bounds__(256) void k_scan2(){
  __shared__ int sh[256];
  int t = threadIdx.x;
  int val = (t < SCAN_B) ? g_partial[t] : 0;
  sh[t] = val;
  __syncthreads();
#pragma unroll
  for (int off = 1; off < 256; off <<= 1){
    int v = (t >= off) ? sh[t - off] : 0;
    __syncthreads();
    sh[t] += v;
    __syncthreads();
  }
  if (t < SCAN_B) g_partial[t] = sh[t] - val;
  if (t == 255) g_rowptr[NN] = sh[255];
}
__global__ __launch_bounds__(256) void k_scan3(){
  int i = blockIdx.x * 256 + threadIdx.x;
  if (i < NN) g_rowptr[i] += g_partial[blockIdx.x];
}

// ---------------- CSR fill
__global__ void k_fill(const int* __restrict__ src, const int* __restrict__ tgt){
  int e = blockIdx.x * 256 + threadIdx.x;
  if (e >= NE) return;
  int t = tgt[e];
  int pos = g_rowptr[t] + atomicAdd(&g_cursor[t], 1);
  g_colidx[pos] = src[e];
}

// ---------------- gather-aggregate, high-MLP (16 lanes/node, x4 unroll)
// MODE 0: plain sum from bufB (RGCN). MODE 1: normalized from bufC (conv1).
template<int MODE>
__global__ __launch_bounds__(256) void k_agg(){
  const unsigned short* x = (MODE == 1) ? g_bufC : g_bufB;
  int node = blockIdx.x * 16 + (threadIdx.x >> 4);
  if (node >= NN) return;
  const int c8 = (threadIdx.x & 15) * 8;

  float wt = (MODE != 0) ? g_dinv[node] : 1.f;
  float a[4][8];
#pragma unroll
  for (int j = 0; j < 4; j++)
#pragma unroll
    for (int k = 0; k < 8; k++) a[j][k] = 0.f;

  int p0 = g_rowptr[node], p1 = g_rowptr[node + 1];
  for (int p = p0; p < p1; p += 4){
    int   sj[4]; float wj[4];
#pragma unroll
    for (int j = 0; j < 4; j++){
      bool ok = (p + j) < p1;
      sj[j] = ok ? g_colidx[p + j] : node;
      wj[j] = ok ? ((MODE != 0) ? g_dinv[sj[j]] * wt : 1.f) : 0.f;
    }
    ushort8 r[4];
#pragma unroll
    for (int j = 0; j < 4; j++)
      r[j] = *reinterpret_cast<const ushort8*>(&x[(size_t)sj[j] * 128 + c8]);
#pragma unroll
    for (int j = 0; j < 4; j++)
#pragma unroll
      for (int k = 0; k < 8; k++) a[j][k] += wj[j] * b2f((unsigned short)r[j][k]);
  }
  if (MODE != 0){
    float ws = wt * wt;
    ushort8 sv = *reinterpret_cast<const ushort8*>(&x[(size_t)node * 128 + c8]);
#pragma unroll
    for (int k = 0; k < 8; k++) a[0][k] += ws * b2f((unsigned short)sv[k]);
  }
  ushort8 o;
#pragma unroll
  for (int k = 0; k < 8; k++)
    o[k] = f2b(a[0][k] + a[1][k] + a[2][k] + a[3][k]);
  *reinterpret_cast<ushort8*>(&g_bufA[(size_t)node * 128 + c8]) = o;
}

// ---------------- GEMM1 (data_x [N,500] -> bufA), K-SPLIT:
// block = 4 waves x SAME 16 rows; wave w owns K in [128w, 128w+128).
// Each lane's 8x16B loads are ALL issued before any MFMA (no interleaving
// constraint -> guaranteed MLP=8). Partials reduced via LDS [val][tid]
// (consecutive-lane addresses, conflict-free); wave 0 does LN epilogue.
// K-tail: load col clamped to 496 (aligned, in-bounds); clamped lanes'
// logical k >= 500 hits W1t zero-pad -> contributes 0.
__global__ __launch_bounds__(256, 4) void k_gemm1_ln(const void* __restrict__ Aext,
    const void* __restrict__ bias, const void* __restrict__ gamma,
    const void* __restrict__ beta){
  __shared__ float red[28 * 256];
  const int tid = threadIdx.x;
  const int w = tid >> 6, lane = tid & 63;
  const int m = lane & 15, q = lane >> 4;
  const int row0 = blockIdx.x * 16;      // 3125 * 16 = 50000 exact
  const int isf32 = g_isf32;
  const int kbase = w * 128;
  f32x4 acc[7] = {};

  if (isf32){
    const float* base = (const float*)Aext + (size_t)(row0 + m) * 500;
    f32x4 L[8];
#pragma unroll
    for (int c = 0; c < 4; c++){
      int col = kbase + c * 32 + q * 8;
      L[2 * c]     = *reinterpret_cast<const f32x4*>(base + min(col, 496));
      L[2 * c + 1] = *reinterpret_cast<const f32x4*>(base + min(col + 4, 496));
    }
#pragma unroll
    for (int c = 0; c < 4; c++){
      f32x4 lo = L[2 * c], hi = L[2 * c + 1];
      short8 a = {(short)f2b(lo[0]), (short)f2b(lo[1]), (short)f2b(lo[2]), (short)f2b(lo[3]),
                  (short)f2b(hi[0]), (short)f2b(hi[1]), (short)f2b(hi[2]), (short)f2b(hi[3])};
      const int k0 = kbase + c * 32 + q * 8;
#pragma unroll
      for (int t = 0; t < 7; t++){
        short8 b = *reinterpret_cast<const short8*>(g_W1t + (size_t)(t * 16 + m) * 512 + k0);
        acc[t] = MFMA16x16x32(a, b, acc[t], 0, 0, 0);
      }
    }
  } else {
    const unsigned short* base = (const unsigned short*)Aext + (size_t)(row0 + m) * 500;
    ushort4 U[8];
#pragma unroll
    for (int c = 0; c < 4; c++){
      int col = kbase + c * 32 + q * 8;
      U[2 * c]     = *reinterpret_cast<const ushort4*>(base + min(col, 496));
      U[2 * c + 1] = *reinterpret_cast<const ushort4*>(base + min(col + 4, 496));
    }
#pragma unroll
    for (int c = 0; c < 4; c++){
      ushort4 lo = U[2 * c], hi = U[2 * c + 1];
      short8 a = {(short)lo.x, (short)lo.y, (short)lo.z, (short)lo.w,
                  (short)hi.x, (short)hi.y, (short)hi.z, (short)hi.w};
      const int k0 = kbase + c * 32 + q * 8;
#pragma unroll
      for (int t = 0; t < 7; t++){
        short8 b = *reinterpret_cast<const short8*>(g_W1t + (size_t)(t * 16 + m) * 512 + k0);
        acc[t] = MFMA16x16x32(a, b, acc[t], 0, 0, 0);
      }
    }
  }

  // cross-wave reduction: red[val][tid], consecutive-lane = conflict-free
#pragma unroll
  for (int t = 0; t < 7; t++)
#pragma unroll
    for (int r = 0; r < 4; r++)
      red[(t * 4 + r) * 256 + tid] = acc[t][r];
  __syncthreads();
  if (w != 0) return;

  float bf_[7], gf_[7], ef_[7];
#pragma unroll
  for (int t = 0; t < 7; t++){
    int col = t * 16 + m;
    bool ok = col < 100;
    bf_[t] = ok ? ld_in(bias, col, isf32)  : 0.f;
    gf_[t] = ok ? ld_in(gamma, col, isf32) : 0.f;
    ef_[t] = ok ? ld_in(beta, col, isf32)  : 0.f;
  }
#pragma unroll
  for (int r = 0; r < 4; r++){
    float vals[7], s1 = 0.f, s2 = 0.f;
#pragma unroll
    for (int t = 0; t < 7; t++){
      const float* rv = &red[(t * 4 + r) * 256];
      float v = rv[lane] + rv[64 + lane] + rv[128 + lane] + rv[192 + lane];
      int col = t * 16 + m;
      v = (col < 100) ? (v + bf_[t]) : 0.f;
      vals[t] = v; s1 += v; s2 += v * v;
    }
#pragma unroll
    for (int msk = 1; msk < 16; msk <<= 1){
      s1 += __shfl_xor(s1, msk, 64);
      s2 += __shfl_xor(s2, msk, 64);
    }
    float mu = s1 * 0.01f;
    float var = fmaxf(s2 * 0.01f - mu * mu, 0.f);
    float rstd = rsqrtf(var + 1e-5f);
    unsigned short* orow = g_bufA + (size_t)(row0 + q * 4 + r) * 128;
#pragma unroll
    for (int t = 0; t < 7; t++){
      int col = t * 16 + m;
      float y = fmaxf((vals[t] - mu) * rstd * gf_[t] + ef_[t], 0.f);
      orow[col] = f2b((col < 100) ? y : 0.f);
    }
    orow[112 + m] = 0;
  }
}

// ---------------- GEMM2 + LN + ReLU (bufA [N,128] @ W2t -> bufB)
__global__ __launch_bounds__(256) void k_gemm2_ln(const void* __restrict__ bias,
    const void* __restrict__ gamma, const void* __restrict__ beta){
  const int isf32 = g_isf32;
  const int wave = threadIdx.x >> 6, lane = threadIdx.x & 63;
  const int m = lane & 15, q = lane >> 4;
  const int row0 = (blockIdx.x * 4 + wave) * 16;
  if (row0 >= NN) return;
  f32x4 acc[7] = {};
  const unsigned short* arow = g_bufA + (size_t)(row0 + m) * 128;
#pragma unroll
  for (int c = 0; c < 4; c++){
    const int k0 = c * 32 + q * 8;
    short8 a = *reinterpret_cast<const short8*>(arow + k0);
#pragma unroll
    for (int t = 0; t < 7; t++){
      short8 b = *reinterpret_cast<const short8*>(g_W2t + (size_t)(t * 16 + m) * 128 + k0);
      acc[t] = MFMA16x16x32(a, b, acc[t], 0, 0, 0);
    }
  }
  float bf_[7], gf_[7], ef_[7];
#pragma unroll
  for (int t = 0; t < 7; t++){
    int col = t * 16 + m;
    bool ok = col < 100;
    bf_[t] = ok ? ld_in(bias, col, isf32)  : 0.f;
    gf_[t] = ok ? ld_in(gamma, col, isf32) : 0.f;
    ef_[t] = ok ? ld_in(beta, col, isf32)  : 0.f;
  }
#pragma unroll
  for (int r = 0; r < 4; r++){
    float vals[7], s1 = 0.f, s2 = 0.f;
#pragma unroll
    for (int t = 0; t < 7; t++){
      int col = t * 16 + m;
      float v = (col < 100) ? (acc[t][r] + bf_[t]) : 0.f;
      vals[t] = v; s1 += v; s2 += v * v;
    }
#pragma unroll
    for (int msk = 1; msk < 16; msk <<= 1){
      s1 += __shfl_xor(s1, msk, 64);
      s2 += __shfl_xor(s2, msk, 64);
    }
    float mu = s1 * 0.01f;
    float var = fmaxf(s2 * 0.01f - mu * mu, 0.f);
    float rstd = rsqrtf(var + 1e-5f);
    unsigned short* orow = g_bufB + (size_t)(row0 + q * 4 + r) * 128;
#pragma unroll
    for (int t = 0; t < 7; t++){
      int col = t * 16 + m;
      float y = fmaxf((vals[t] - mu) * rstd * gf_[t] + ef_[t], 0.f);
      orow[col] = f2b((col < 100) ? y : 0.f);
    }
    orow[112 + m] = 0;
  }
}

// ---------------- (A1@B1t [+ A2@B2t]) + bias, ReLU. K=128.
template<int SEL>
__global__ __launch_bounds__(256) void k_gemm_bias_relu(const void* __restrict__ bias){
  const unsigned short* A1  = (SEL == 0) ? g_bufB : g_bufA;
  const unsigned short* B1t = (SEL == 0) ? g_WselfT : g_c1Wt;
  unsigned short* out       = (SEL == 0) ? g_bufC : g_bufB;
  const int isf32 = g_isf32;

  const int wave = threadIdx.x >> 6, lane = threadIdx.x & 63;
  const int m = lane & 15, q = lane >> 4;
  const int row0 = (blockIdx.x * 4 + wave) * 16;
  if (row0 >= NN) return;
  f32x4 acc[7] = {};
  const unsigned short* a1row = A1 + (size_t)(row0 + m) * 128;
#pragma unroll
  for (int c = 0; c < 4; c++){
    const int k0 = c * 32 + q * 8;
    short8 a = *reinterpret_cast<const short8*>(a1row + k0);
#pragma unroll
    for (int t = 0; t < 7; t++){
      short8 b = *reinterpret_cast<const short8*>(B1t + (size_t)(t * 16 + m) * 128 + k0);
      acc[t] = MFMA16x16x32(a, b, acc[t], 0, 0, 0);
    }
  }
  if (SEL == 0){
    const unsigned short* a2row = g_bufA + (size_t)(row0 + m) * 128;
#pragma unroll
    for (int c = 0; c < 4; c++){
      const int k0 = c * 32 + q * 8;
      short8 a = *reinterpret_cast<const short8*>(a2row + k0);
#pragma unroll
      for (int t = 0; t < 7; t++){
        short8 b = *reinterpret_cast<const short8*>(g_WrelT + (size_t)(t * 16 + m) * 128 + k0);
        acc[t] = MFMA16x16x32(a, b, acc[t], 0, 0, 0);
      }
    }
  }
  float bf_[7];
#pragma unroll
  for (int t = 0; t < 7; t++){
    int col = t * 16 + m;
    bf_[t] = (col < 100) ? ld_in(bias, col, isf32) : 0.f;
  }
#pragma unroll
  for (int r = 0; r < 4; r++){
    unsigned short* orow = out + (size_t)(row0 + q * 4 + r) * 128;
#pragma unroll
    for (int t = 0; t < 7; t++){
      int col = t * 16 + m;
      float y = fmaxf(acc[t][r] + bf_[t], 0.f);
      orow[col] = f2b((col < 100) ? y : 0.f);
    }
    orow[112 + m] = 0;
  }
}

// ---------------- conv2 GEMM only: bufB [N,128] @ c2Wt -> bufC [N,64] bf16
// (bias applied AFTER aggregation, in k_agg_lsm — matches PyG GCNConv)
__global__ __launch_bounds__(256) void k_gemm_c2(){
  const int wave = threadIdx.x >> 6, lane = threadIdx.x & 63;
  const int m = lane & 15, q = lane >> 4;
  const int row0 = (blockIdx.x * 4 + wave) * 16;
  if (row0 >= NN) return;
  f32x4 acc[4] = {};
  const unsigned short* arow = g_bufB + (size_t)(row0 + m) * 128;
#pragma unroll
  for (int c = 0; c < 4; c++){
    const int k0 = c * 32 + q * 8;
    short8 a = *reinterpret_cast<const short8*>(arow + k0);
#pragma unroll
    for (int t = 0; t < 4; t++){
      short8 b = *reinterpret_cast<const short8*>(g_c2Wt + (size_t)(t * 16 + m) * 128 + k0);
      acc[t] = MFMA16x16x32(a, b, acc[t], 0, 0, 0);
    }
  }
#pragma unroll
  for (int r = 0; r < 4; r++){
    unsigned short* orow = g_bufC + (size_t)(row0 + q * 4 + r) * 64;
#pragma unroll
    for (int t = 0; t < 4; t++) orow[t * 16 + m] = f2b(acc[t][r]);
  }
}

// ---------------- conv2 aggregate (64-col, 128B rows) + bias + log_softmax
// 8 lanes/node, 32 nodes/block; softmax reduce via shfl_xor {1,2,4} within
// the 8-aligned lane group.
__global__ __launch_bounds__(256) void k_agg_lsm(const void* __restrict__ bias,
                                                 void* __restrict__ outv){
  const int isf32 = g_isf32;
  int node = blockIdx.x * 32 + (threadIdx.x >> 3);
  if (node >= NN) return;
  const int c8 = (threadIdx.x & 7) * 8;
  float wt = g_dinv[node];
  float a[4][8];
#pragma unroll
  for (int j = 0; j < 4; j++)
#pragma unroll
    for (int k = 0; k < 8; k++) a[j][k] = 0.f;

  int p0 = g_rowptr[node], p1 = g_rowptr[node + 1];
  for (int p = p0; p < p1; p += 4){
    int   sj[4]; float wj[4];
#pragma unroll
    for (int j = 0; j < 4; j++){
      bool ok = (p + j) < p1;
      sj[j] = ok ? g_colidx[p + j] : node;
      wj[j] = ok ? g_dinv[sj[j]] * wt : 0.f;
    }
    ushort8 r[4];
#pragma unroll
    for (int j = 0; j < 4; j++)
      r[j] = *reinterpret_cast<const ushort8*>(&g_bufC[(size_t)sj[j] * 64 + c8]);
#pragma unroll
    for (int j = 0; j < 4; j++)
#pragma unroll
      for (int k = 0; k < 8; k++) a[j][k] += wj[j] * b2f((unsigned short)r[j][k]);
  }
  float ws = wt * wt;
  ushort8 sv = *reinterpret_cast<const ushort8*>(&g_bufC[(size_t)node * 64 + c8]);
#pragma unroll
  for (int k = 0; k < 8; k++) a[0][k] += ws * b2f((unsigned short)sv[k]);

  float v[8], mx = -1e30f;
#pragma unroll
  for (int k = 0; k < 8; k++){
    v[k] = a[0][k] + a[1][k] + a[2][k] + a[3][k] + ld_in(bias, c8 + k, isf32);
    mx = fmaxf(mx, v[k]);
  }
#pragma unroll
  for (int msk = 1; msk < 8; msk <<= 1) mx = fmaxf(mx, __shfl_xor(mx, msk, 64));
  float se = 0.f;
#pragma unroll
  for (int k = 0; k < 8; k++) se += expf(v[k] - mx);
#pragma unroll
  for (int msk = 1; msk < 8; msk <<= 1) se += __shfl_xor(se, msk, 64);
  float lse = logf(se);
  size_t ro = (size_t)node * 64 + c8;
  if (isf32){
    float* o = (float*)outv + ro;
#pragma unroll
    for (int k = 0; k < 8; k++) o[k] = v[k] - mx - lse;
  } else {
    unsigned short* o = (unsigned short*)outv + ro;
#pragma unroll
    for (int k = 0; k < 8; k++) o[k] = f2b(v[k] - mx - lse);
  }
}

extern "C" void kernel_launch(void* const* d_in, const int* in_sizes, int n_in,
                              void* d_out, int out_size, void* d_ws, size_t ws_size,
                              hipStream_t stream){
  (void)in_sizes; (void)n_in; (void)out_size; (void)d_ws; (void)ws_size;
  const void* data_x = d_in[0];
  const int* ei = (const int*)d_in[1];
  const int* src = ei;
  const int* tgt = ei + NE;
  const void *W1 = d_in[3], *b1 = d_in[4], *gm1 = d_in[5], *be1 = d_in[6];
  const void *W2 = d_in[7], *b2 = d_in[8], *gm2 = d_in[9], *be2 = d_in[10];
  const void *Wrel = d_in[11], *Wself = d_in[12], *rb = d_in[13];
  const void *c1W = d_in[14], *c1b = d_in[15];
  const void *c2W = d_in[16], *c2b = d_in[17];

  k_detect<<<1, 256, 0, stream>>>((const unsigned short*)data_x);
  k_zero<<<(NN + 255) / 256, 256, 0, stream>>>();
  k_transpose_all<<<(122880 + 255) / 256, 256, 0, stream>>>(W1, W2, Wself, Wrel, c1W, c2W);

  k_deg<<<(NE + 255) / 256, 256, 0, stream>>>(tgt);
  k_scan1<<<SCAN_B, 256, 0, stream>>>();
  k_scan2<<<1, 256, 0, stream>>>();
  k_scan3<<<SCAN_B, 256, 0, stream>>>();
  k_fill<<<(NE + 255) / 256, 256, 0, stream>>>(src, tgt);

  const int G64 = (NN + 63) / 64;     // 782 blocks, 4 waves x 16 rows
  const int GA  = (NN + 15) / 16;     // 3125 blocks, 16 nodes/block
  k_gemm1_ln<<<3125, 256, 0, stream>>>(data_x, b1, gm1, be1);  // data_x -> bufA (K-split)
  k_gemm2_ln<<<G64, 256, 0, stream>>>(b2, gm2, be2);           // bufA -> bufB
  k_agg<0><<<GA, 256, 0, stream>>>();                          // bufB -> bufA (RGCN sum)
  k_gemm_bias_relu<0><<<G64, 256, 0, stream>>>(rb);            // bufB@Wself + bufA@Wrel -> bufC
  k_agg<1><<<GA, 256, 0, stream>>>();                          // bufC -> bufA (GCN norm)
  k_gemm_bias_relu<1><<<G64, 256, 0, stream>>>(c1b);           // bufA@c1W -> bufB
  k_gemm_c2<<<G64, 256, 0, stream>>>();                        // bufB@c2W -> bufC [N,64]
  k_agg_lsm<<<(NN + 31) / 32, 256, 0, stream>>>(c2b, d_out);   // agg + bias + lsm -> out
}